// Round 1
// baseline (306.301 us; speedup 1.0000x reference)
//
#include <hip/hip_runtime.h>
#include <math.h>

#define NB 8
#define NC 256
#define HS 64
#define WSM 64
#define HL 512
#define WL 512
#define NK 21
#define PS (HS*WSM)     /* 4096 */
#define PL (HL*WL)      /* 262144 */

// ws layout (floats):
//   seg: [B,K,PS]    off 0        size 688128
//   T1:  [B,3,HL,WSM] off 688128  size 786432
//   A:   [B,3,PS]    off 1474560  size 98304
//   q:   [B,K,3]     off 1572864  size 504
// total ~6.3 MB

__global__ __launch_bounds__(128) void k_logits_softmax(
    const float* __restrict__ fm, const float* __restrict__ Wc,
    const float* __restrict__ bc, float* __restrict__ seg)
{
    __shared__ float sW[NK*NC];
    __shared__ float sB[NK];
    int tid = threadIdx.x;
    for (int i = tid; i < NK*NC; i += 128) sW[i] = Wc[i];
    if (tid < NK) sB[tid] = bc[tid];
    __syncthreads();

    int b = blockIdx.y;
    int p = blockIdx.x * 128 + tid;

    float logit[NK];
    #pragma unroll
    for (int k = 0; k < NK; ++k) logit[k] = sB[k];

    const float* fmb = fm + (size_t)b * NC * PS + p;
    for (int c = 0; c < NC; ++c) {
        float v = fmb[(size_t)c * PS];
        #pragma unroll
        for (int k = 0; k < NK; ++k) logit[k] += v * sW[k*NC + c];
    }
    float m = logit[0];
    #pragma unroll
    for (int k = 1; k < NK; ++k) m = fmaxf(m, logit[k]);
    float s = 0.f;
    #pragma unroll
    for (int k = 0; k < NK; ++k) { logit[k] = __expf(logit[k] - m); s += logit[k]; }
    float inv = 1.f / s;
    float* segb = seg + (size_t)b * NK * PS + p;
    #pragma unroll
    for (int k = 0; k < NK; ++k) segb[(size_t)k*PS] = logit[k] * inv;
}

// horizontal adjoint: T1[b,c,Y,w] = sum_X wgt(w<-X) * x[b,c,Y,X]
__global__ __launch_bounds__(64) void k_adj_x(
    const float* __restrict__ x, float* __restrict__ T1)
{
    __shared__ float row[WL];
    int rowid = blockIdx.x;              // b*3*HL + c*HL + Y
    const float* src = x + (size_t)rowid * WL;
    int tid = threadIdx.x;
    for (int i = tid; i < WL; i += 64) row[i] = src[i];
    __syncthreads();

    const int w = tid;                   // 0..63
    const float scale = 63.0f / 511.0f;
    const float inv_scale = 511.0f / 63.0f;
    int Xlo = max(0,    (int)floorf((w - 1) * inv_scale) - 1);
    int Xhi = min(WL-1, (int)ceilf ((w + 1) * inv_scale) + 1);
    float acc = 0.f;
    for (int X = Xlo; X <= Xhi; ++X) {
        float fs = X * scale;
        int i0 = (int)fs; if (i0 > WSM-1) i0 = WSM-1;
        float f = fs - (float)i0;
        int i1 = min(i0 + 1, WSM-1);
        float wt = (i0 == w ? 1.f - f : 0.f) + (i1 == w ? f : 0.f);
        acc += wt * row[X];
    }
    T1[(size_t)rowid * WSM + w] = acc;
}

// vertical adjoint: A[b,c,h,w] = sum_Y wgt(h<-Y) * T1[b,c,Y,w]
__global__ __launch_bounds__(256) void k_adj_y(
    const float* __restrict__ T1, float* __restrict__ A)
{
    int g = blockIdx.x * 256 + threadIdx.x;   // B*3*PS = 98304
    int w = g & (WSM-1);
    int h = (g >> 6) & (HS-1);
    int bcid = g >> 12;                        // 0..23
    const float scale = 63.0f / 511.0f;
    const float inv_scale = 511.0f / 63.0f;
    int Ylo = max(0,    (int)floorf((h - 1) * inv_scale) - 1);
    int Yhi = min(HL-1, (int)ceilf ((h + 1) * inv_scale) + 1);
    const float* src = T1 + (size_t)bcid * HL * WSM + w;
    float acc = 0.f;
    for (int Y = Ylo; Y <= Yhi; ++Y) {
        float fs = Y * scale;
        int i0 = (int)fs; if (i0 > HS-1) i0 = HS-1;
        float f = fs - (float)i0;
        int i1 = min(i0 + 1, HS-1);
        float wt = (i0 == h ? 1.f - f : 0.f) + (i1 == h ? f : 0.f);
        acc += wt * src[(size_t)Y * WSM];
    }
    A[g] = acc;
}

// q[b,k,c] = (1/PL) * sum_p seg[b,k,p] * A[b,c,p]
__global__ __launch_bounds__(256) void k_q(
    const float* __restrict__ seg, const float* __restrict__ A,
    float* __restrict__ q)
{
    int bk = blockIdx.x;          // b*K + k
    int b = bk / NK;
    int tid = threadIdx.x;
    const float* s = seg + (size_t)bk * PS;
    const float* Ab = A + (size_t)b * 3 * PS;
    float a0 = 0.f, a1 = 0.f, a2 = 0.f;
    for (int p = tid; p < PS; p += 256) {
        float sv = s[p];
        a0 += sv * Ab[p];
        a1 += sv * Ab[PS + p];
        a2 += sv * Ab[2*PS + p];
    }
    #pragma unroll
    for (int off = 32; off > 0; off >>= 1) {
        a0 += __shfl_down(a0, off);
        a1 += __shfl_down(a1, off);
        a2 += __shfl_down(a2, off);
    }
    __shared__ float red[4][3];
    int wave = tid >> 6;
    if ((tid & 63) == 0) { red[wave][0] = a0; red[wave][1] = a1; red[wave][2] = a2; }
    __syncthreads();
    if (tid == 0) {
        float r0 = 0.f, r1 = 0.f, r2 = 0.f;
        #pragma unroll
        for (int i = 0; i < 4; ++i) { r0 += red[i][0]; r1 += red[i][1]; r2 += red[i][2]; }
        const float inv = 1.0f / (float)PL;
        q[bk*3+0] = r0 * inv; q[bk*3+1] = r1 * inv; q[bk*3+2] = r2 * inv;
    }
}

// out[b,k,p] = sum_c x[b,c,p] * q[b,k,c]  (float4 over p)
__global__ __launch_bounds__(256) void k_out(
    const float* __restrict__ x, const float* __restrict__ q,
    float* __restrict__ out)
{
    __shared__ float sq[NK*3];
    int tid = threadIdx.x;
    int b = blockIdx.y;
    if (tid < NK*3) sq[tid] = q[b*NK*3 + tid];
    __syncthreads();

    int p4 = blockIdx.x * 256 + tid;          // 65536 float4 per image
    const float4* xb = (const float4*)(x + (size_t)b * 3 * PL);
    float4 x0 = xb[p4];
    float4 x1 = xb[PL/4 + p4];
    float4 x2 = xb[2*(PL/4) + p4];
    float4* ob = (float4*)(out + (size_t)b * NK * PL);
    #pragma unroll
    for (int k = 0; k < NK; ++k) {
        float q0 = sq[k*3+0], q1 = sq[k*3+1], q2 = sq[k*3+2];
        float4 o;
        o.x = q0*x0.x + q1*x1.x + q2*x2.x;
        o.y = q0*x0.y + q1*x1.y + q2*x2.y;
        o.z = q0*x0.z + q1*x1.z + q2*x2.z;
        o.w = q0*x0.w + q1*x1.w + q2*x2.w;
        ob[(size_t)k * (PL/4) + p4] = o;
    }
}

extern "C" void kernel_launch(void* const* d_in, const int* in_sizes, int n_in,
                              void* d_out, int out_size, void* d_ws, size_t ws_size,
                              hipStream_t stream)
{
    const float* fm = (const float*)d_in[0];   // [8,256,64,64]
    const float* x  = (const float*)d_in[1];   // [8,3,512,512]
    const float* Wc = (const float*)d_in[2];   // [21,256]
    const float* bc = (const float*)d_in[3];   // [21]
    float* out = (float*)d_out;                // [8,21,512,512]

    float* ws  = (float*)d_ws;
    float* seg = ws;                  // 688128
    float* T1  = seg + 688128;        // 786432
    float* A   = T1 + 786432;         // 98304
    float* q   = A + 98304;           // 504

    k_logits_softmax<<<dim3(PS/128, NB), 128, 0, stream>>>(fm, Wc, bc, seg);
    k_adj_x<<<NB*3*HL, 64, 0, stream>>>(x, T1);
    k_adj_y<<<NB*3*PS/256, 256, 0, stream>>>(T1, A);
    k_q<<<NB*NK, 256, 0, stream>>>(seg, A, q);
    k_out<<<dim3(PL/4/256, NB), 256, 0, stream>>>(x, q, out);
}

// Round 2
// 305.240 us; speedup vs baseline: 1.0035x; 1.0035x over previous
//
#include <hip/hip_runtime.h>
#include <math.h>

#define NB 8
#define NC 256
#define HS 64
#define WSM 64
#define HL 512
#define WL 512
#define NK 21
#define PS (HS*WSM)     /* 4096 */
#define PL (HL*WL)      /* 262144 */

// ws layout (floats):
//   Wt:  [256][32]  (c-major, padded)   off 0       size 8192
//   T1:  [B,3,HL,WSM]                   off 8192    size 786432
//   A:   [B,3,PS]                       off 794624  size 98304
//   q:   [B,K,3]                        off 892928  size 504
// total ~3.6 MB

// transpose W_cls [21,256] -> Wt [256,32] (c-major, padded stride 32)
__global__ __launch_bounds__(256) void k_wt(
    const float* __restrict__ Wc, float* __restrict__ Wt)
{
    int i = blockIdx.x * 256 + threadIdx.x;
    if (i < NK*NC) {
        int c = i / NK;
        int k = i - c*NK;
        Wt[c*32 + k] = Wc[k*NC + c];
    }
}

// horizontal adjoint: T1[b,c,Y,w] = sum_X wgt(w<-X) * x[b,c,Y,X]
__global__ __launch_bounds__(64) void k_adj_x(
    const float* __restrict__ x, float* __restrict__ T1)
{
    __shared__ float row[WL];
    int rowid = blockIdx.x;              // b*3*HL + c*HL + Y
    const float* src = x + (size_t)rowid * WL;
    int tid = threadIdx.x;
    for (int i = tid; i < WL; i += 64) row[i] = src[i];
    __syncthreads();

    const int w = tid;                   // 0..63
    const float scale = 63.0f / 511.0f;
    const float inv_scale = 511.0f / 63.0f;
    int Xlo = max(0,    (int)floorf((w - 1) * inv_scale) - 1);
    int Xhi = min(WL-1, (int)ceilf ((w + 1) * inv_scale) + 1);
    float acc = 0.f;
    for (int X = Xlo; X <= Xhi; ++X) {
        float fs = X * scale;
        int i0 = (int)fs; if (i0 > WSM-1) i0 = WSM-1;
        float f = fs - (float)i0;
        int i1 = min(i0 + 1, WSM-1);
        float wt = (i0 == w ? 1.f - f : 0.f) + (i1 == w ? f : 0.f);
        acc += wt * row[X];
    }
    T1[(size_t)rowid * WSM + w] = acc;
}

// vertical adjoint: A[b,c,h,w] = sum_Y wgt(h<-Y) * T1[b,c,Y,w]
__global__ __launch_bounds__(256) void k_adj_y(
    const float* __restrict__ T1, float* __restrict__ A)
{
    int g = blockIdx.x * 256 + threadIdx.x;   // B*3*PS = 98304
    int w = g & (WSM-1);
    int h = (g >> 6) & (HS-1);
    int bcid = g >> 12;                        // 0..23
    const float scale = 63.0f / 511.0f;
    const float inv_scale = 511.0f / 63.0f;
    int Ylo = max(0,    (int)floorf((h - 1) * inv_scale) - 1);
    int Yhi = min(HL-1, (int)ceilf ((h + 1) * inv_scale) + 1);
    const float* src = T1 + (size_t)bcid * HL * WSM + w;
    float acc = 0.f;
    for (int Y = Ylo; Y <= Yhi; ++Y) {
        float fs = Y * scale;
        int i0 = (int)fs; if (i0 > HS-1) i0 = HS-1;
        float f = fs - (float)i0;
        int i1 = min(i0 + 1, HS-1);
        float wt = (i0 == h ? 1.f - f : 0.f) + (i1 == h ? f : 0.f);
        acc += wt * src[(size_t)Y * WSM];
    }
    A[g] = acc;
}

// fused: logits (W from SGPRs via uniform loads) + softmax + q-reduction.
// q[b,k,c] += sum over this wave's 64 pixels of seg[k]*A[c]; scaled by 1/PL in k_out.
__global__ __launch_bounds__(64) void k_fused(
    const float* __restrict__ fm, const float* __restrict__ Wt,
    const float* __restrict__ bc, const float* __restrict__ A,
    float* __restrict__ q)
{
    int b = blockIdx.y;
    int p = blockIdx.x * 64 + threadIdx.x;

    float logit[NK];
    #pragma unroll
    for (int k = 0; k < NK; ++k) logit[k] = bc[k];   // uniform -> s_load

    const float* fmb = fm + (size_t)b * NC * PS + p;
    #pragma unroll 4
    for (int c = 0; c < NC; ++c) {
        float v = fmb[(size_t)c * PS];
        const float* w = Wt + c * 32;                // uniform address -> s_load
        #pragma unroll
        for (int k = 0; k < NK; ++k) logit[k] = fmaf(v, w[k], logit[k]);
    }

    float m = logit[0];
    #pragma unroll
    for (int k = 1; k < NK; ++k) m = fmaxf(m, logit[k]);
    float s = 0.f;
    #pragma unroll
    for (int k = 0; k < NK; ++k) { logit[k] = __expf(logit[k] - m); s += logit[k]; }
    float inv = 1.f / s;

    const float* Ab = A + (size_t)b * 3 * PS + p;
    float a0 = Ab[0], a1 = Ab[PS], a2 = Ab[2*PS];

    float* qb = q + b * NK * 3;
    #pragma unroll
    for (int k = 0; k < NK; ++k) {
        float sv = logit[k] * inv;
        float r0 = sv * a0, r1 = sv * a1, r2 = sv * a2;
        #pragma unroll
        for (int off = 32; off; off >>= 1) {
            r0 += __shfl_down(r0, off);
            r1 += __shfl_down(r1, off);
            r2 += __shfl_down(r2, off);
        }
        if (threadIdx.x == 0) {
            atomicAdd(qb + k*3 + 0, r0);
            atomicAdd(qb + k*3 + 1, r1);
            atomicAdd(qb + k*3 + 2, r2);
        }
    }
}

// out[b,k,p] = sum_c x[b,c,p] * q[b,k,c]/PL   (float4 over p)
__global__ __launch_bounds__(256) void k_out(
    const float* __restrict__ x, const float* __restrict__ q,
    float* __restrict__ out)
{
    __shared__ float sq[NK*3];
    int tid = threadIdx.x;
    int b = blockIdx.y;
    if (tid < NK*3) sq[tid] = q[b*NK*3 + tid] * (1.0f / (float)PL);
    __syncthreads();

    int p4 = blockIdx.x * 256 + tid;          // 65536 float4 per image
    const float4* xb = (const float4*)(x + (size_t)b * 3 * PL);
    float4 x0 = xb[p4];
    float4 x1 = xb[PL/4 + p4];
    float4 x2 = xb[2*(PL/4) + p4];
    float4* ob = (float4*)(out + (size_t)b * NK * PL);
    #pragma unroll
    for (int k = 0; k < NK; ++k) {
        float q0 = sq[k*3+0], q1 = sq[k*3+1], q2 = sq[k*3+2];
        float4 o;
        o.x = q0*x0.x + q1*x1.x + q2*x2.x;
        o.y = q0*x0.y + q1*x1.y + q2*x2.y;
        o.z = q0*x0.z + q1*x1.z + q2*x2.z;
        o.w = q0*x0.w + q1*x1.w + q2*x2.w;
        ob[(size_t)k * (PL/4) + p4] = o;
    }
}

extern "C" void kernel_launch(void* const* d_in, const int* in_sizes, int n_in,
                              void* d_out, int out_size, void* d_ws, size_t ws_size,
                              hipStream_t stream)
{
    const float* fm = (const float*)d_in[0];   // [8,256,64,64]
    const float* x  = (const float*)d_in[1];   // [8,3,512,512]
    const float* Wc = (const float*)d_in[2];   // [21,256]
    const float* bc = (const float*)d_in[3];   // [21]
    float* out = (float*)d_out;                // [8,21,512,512]

    float* ws = (float*)d_ws;
    float* Wt = ws;                   // 8192
    float* T1 = Wt + 8192;            // 786432
    float* A  = T1 + 786432;          // 98304
    float* q  = A + 98304;            // 504

    hipMemsetAsync(q, 0, NB*NK*3*sizeof(float), stream);
    k_wt<<<(NK*NC + 255)/256, 256, 0, stream>>>(Wc, Wt);
    k_adj_x<<<NB*3*HL, 64, 0, stream>>>(x, T1);
    k_adj_y<<<NB*3*PS/256, 256, 0, stream>>>(T1, A);
    k_fused<<<dim3(PS/64, NB), 64, 0, stream>>>(fm, Wt, bc, A, q);
    k_out<<<dim3(PL/4/256, NB), 256, 0, stream>>>(x, q, out);
}

// Round 4
// 300.770 us; speedup vs baseline: 1.0184x; 1.0149x over previous
//
#include <hip/hip_runtime.h>
#include <math.h>

#define NB 8
#define NC 256
#define HS 64
#define WSM 64
#define HL 512
#define WL 512
#define NK 21
#define PS (HS*WSM)     /* 4096 */
#define PL (HL*WL)      /* 262144 */

#define NROWS (NB*3*HL)             /* 12288 adj_x rows */
#define WT_ELEMS (NK*NC)            /* 5376 */
#define WT_BLOCKS ((WT_ELEMS+63)/64) /* 84 */

typedef float fx4 __attribute__((ext_vector_type(4)));

// ws layout (floats):
//   Wt:  [256][32]  (c-major, padded)   off 0       size 8192
//   T1:  [B,3,HL,WSM]                   off 8192    size 786432
//   A:   [B,3,PS]                       off 794624  size 98304
//   q:   [B,K,3]                        off 892928  size 504

// fused prep: adj_x rows + W transpose + q zero-init (independent jobs by blockIdx)
__global__ __launch_bounds__(64) void k_prep(
    const float* __restrict__ x, const float* __restrict__ Wc,
    float* __restrict__ T1, float* __restrict__ Wt, float* __restrict__ q)
{
    int blk = blockIdx.x;
    int tid = threadIdx.x;

    if (blk < NROWS) {
        // horizontal adjoint: T1[row, w] = sum_X wgt(w<-X) * x[row, X]
        __shared__ float row[WL];
        const float* src = x + (size_t)blk * WL;
        for (int i = tid; i < WL; i += 64) row[i] = src[i];
        __syncthreads();

        const int w = tid;
        const float scale = 63.0f / 511.0f;
        const float inv_scale = 511.0f / 63.0f;
        int Xlo = max(0,    (int)floorf((w - 1) * inv_scale) - 1);
        int Xhi = min(WL-1, (int)ceilf ((w + 1) * inv_scale) + 1);
        float acc = 0.f;
        for (int X = Xlo; X <= Xhi; ++X) {
            float fs = X * scale;
            int i0 = (int)fs; if (i0 > WSM-1) i0 = WSM-1;
            float f = fs - (float)i0;
            int i1 = min(i0 + 1, WSM-1);
            float wt = (i0 == w ? 1.f - f : 0.f) + (i1 == w ? f : 0.f);
            acc += wt * row[X];
        }
        T1[(size_t)blk * WSM + w] = acc;
    } else if (blk < NROWS + WT_BLOCKS) {
        // transpose W_cls [21,256] -> Wt [256,32] (c-major, padded stride 32)
        int i = (blk - NROWS) * 64 + tid;
        if (i < WT_ELEMS) {
            int c = i / NK;
            int k = i - c*NK;
            Wt[c*32 + k] = Wc[k*NC + c];
        }
    } else {
        for (int i = tid; i < NB*NK*3; i += 64) q[i] = 0.f;
    }
}

// vertical adjoint: A[b,c,h,w] = sum_Y wgt(h<-Y) * T1[b,c,Y,w]
__global__ __launch_bounds__(256) void k_adj_y(
    const float* __restrict__ T1, float* __restrict__ A)
{
    int g = blockIdx.x * 256 + threadIdx.x;   // B*3*PS = 98304
    int w = g & (WSM-1);
    int h = (g >> 6) & (HS-1);
    int bcid = g >> 12;                        // 0..23
    const float scale = 63.0f / 511.0f;
    const float inv_scale = 511.0f / 63.0f;
    int Ylo = max(0,    (int)floorf((h - 1) * inv_scale) - 1);
    int Yhi = min(HL-1, (int)ceilf ((h + 1) * inv_scale) + 1);
    const float* src = T1 + (size_t)bcid * HL * WSM + w;
    float acc = 0.f;
    for (int Y = Ylo; Y <= Yhi; ++Y) {
        float fs = Y * scale;
        int i0 = (int)fs; if (i0 > HS-1) i0 = HS-1;
        float f = fs - (float)i0;
        int i1 = min(i0 + 1, HS-1);
        float wt = (i0 == h ? 1.f - f : 0.f) + (i1 == h ? f : 0.f);
        acc += wt * src[(size_t)Y * WSM];
    }
    A[g] = acc;
}

// fused: logits (W via uniform s_loads) + softmax + q-reduction.
// q[b,k,c] += sum over this wave's 64 pixels of seg[k]*A[c]; scaled by 1/PL in k_out.
__global__ __launch_bounds__(64) void k_fused(
    const float* __restrict__ fm, const float* __restrict__ Wt,
    const float* __restrict__ bc, const float* __restrict__ A,
    float* __restrict__ q)
{
    int b = blockIdx.y;
    int p = blockIdx.x * 64 + threadIdx.x;

    float logit[NK];
    #pragma unroll
    for (int k = 0; k < NK; ++k) logit[k] = bc[k];   // uniform -> s_load

    const float* fmb = fm + (size_t)b * NC * PS + p;
    #pragma unroll 8
    for (int c = 0; c < NC; ++c) {
        float v = __builtin_nontemporal_load(fmb + (size_t)c * PS);
        const float* w = Wt + c * 32;                // uniform address -> s_load
        #pragma unroll
        for (int k = 0; k < NK; ++k) logit[k] = fmaf(v, w[k], logit[k]);
    }

    float m = logit[0];
    #pragma unroll
    for (int k = 1; k < NK; ++k) m = fmaxf(m, logit[k]);
    float s = 0.f;
    #pragma unroll
    for (int k = 0; k < NK; ++k) { logit[k] = __expf(logit[k] - m); s += logit[k]; }
    float inv = 1.f / s;

    const float* Ab = A + (size_t)b * 3 * PS + p;
    float a0 = Ab[0], a1 = Ab[PS], a2 = Ab[2*PS];

    float* qb = q + b * NK * 3;
    #pragma unroll
    for (int k = 0; k < NK; ++k) {
        float sv = logit[k] * inv;
        float r0 = sv * a0, r1 = sv * a1, r2 = sv * a2;
        #pragma unroll
        for (int off = 32; off; off >>= 1) {
            r0 += __shfl_down(r0, off);
            r1 += __shfl_down(r1, off);
            r2 += __shfl_down(r2, off);
        }
        if (threadIdx.x == 0) {
            atomicAdd(qb + k*3 + 0, r0);
            atomicAdd(qb + k*3 + 1, r1);
            atomicAdd(qb + k*3 + 2, r2);
        }
    }
}

// out[b,k,p] = sum_c x[b,c,p] * q[b,k,c]/PL   (fx4 over p, nontemporal stores)
__global__ __launch_bounds__(256) void k_out(
    const float* __restrict__ x, const float* __restrict__ q,
    float* __restrict__ out)
{
    __shared__ float sq[NK*3];
    int tid = threadIdx.x;
    int b = blockIdx.y;
    if (tid < NK*3) sq[tid] = q[b*NK*3 + tid] * (1.0f / (float)PL);
    __syncthreads();

    int p4 = blockIdx.x * 256 + tid;          // 65536 fx4 per image
    const fx4* xb = (const fx4*)(x + (size_t)b * 3 * PL);
    fx4 x0 = xb[p4];
    fx4 x1 = xb[PL/4 + p4];
    fx4 x2 = xb[2*(PL/4) + p4];
    fx4* ob = (fx4*)(out + (size_t)b * NK * PL);
    #pragma unroll
    for (int k = 0; k < NK; ++k) {
        fx4 o = sq[k*3+0]*x0 + sq[k*3+1]*x1 + sq[k*3+2]*x2;
        __builtin_nontemporal_store(o, ob + (size_t)k * (PL/4) + p4);
    }
}

extern "C" void kernel_launch(void* const* d_in, const int* in_sizes, int n_in,
                              void* d_out, int out_size, void* d_ws, size_t ws_size,
                              hipStream_t stream)
{
    const float* fm = (const float*)d_in[0];   // [8,256,64,64]
    const float* x  = (const float*)d_in[1];   // [8,3,512,512]
    const float* Wc = (const float*)d_in[2];   // [21,256]
    const float* bc = (const float*)d_in[3];   // [21]
    float* out = (float*)d_out;                // [8,21,512,512]

    float* ws = (float*)d_ws;
    float* Wt = ws;                   // 8192
    float* T1 = Wt + 8192;            // 786432
    float* A  = T1 + 786432;          // 98304
    float* q  = A + 98304;            // 504

    k_prep<<<NROWS + WT_BLOCKS + 1, 64, 0, stream>>>(x, Wc, T1, Wt, q);
    k_adj_y<<<NB*3*PS/256, 256, 0, stream>>>(T1, A);
    k_fused<<<dim3(PS/64, NB), 64, 0, stream>>>(fm, Wt, bc, A, q);
    k_out<<<dim3(PL/4/256, NB), 256, 0, stream>>>(x, q, out);
}